// Round 3
// baseline (689.832 us; speedup 1.0000x reference)
//
#include <hip/hip_runtime.h>

#define NBINS 10
// ws layout: [0..9]=cnt, [10..19]=conf_sum, [20..29]=acc_sum, [30]=targets-are-int64 flag

// --- kernel 0: zero accumulators + sniff targets dtype ---
__global__ void ece_zero_ws(float* __restrict__ ws, const int* __restrict__ t) {
    int i = threadIdx.x;
    if (i < 3 * NBINS) ws[i] = 0.0f;
    if (i == 0) {
        // int64 little-endian targets with values in [0,128) -> every odd
        // int32 word is 0. For int32 targets, P(64 odd words all zero) ~ 128^-64.
        bool is64 = true;
        for (int k = 0; k < 64; ++k) {
            if (t[2 * k + 1] != 0) { is64 = false; break; }
        }
        ws[30] = is64 ? 1.0f : 0.0f;
    }
}

// --- kernel 1: per-row conf/pred + binned partial sums ---
// Two rows per wave: lanes 0-31 handle row 2p, lanes 32-63 handle row 2p+1.
// Lane loads a float4 (16 B) -> one 1 KiB coalesced load per wave per row-pair.
__global__ __launch_bounds__(256) void ece_main(const float* __restrict__ logits,
                                                const int* __restrict__ targets,
                                                float* __restrict__ ws, int n) {
    __shared__ float s_cnt[NBINS], s_conf[NBINS], s_acc[NBINS];
    if (threadIdx.x < NBINS) {
        s_cnt[threadIdx.x] = 0.0f;
        s_conf[threadIdx.x] = 0.0f;
        s_acc[threadIdx.x] = 0.0f;
    }
    const bool t64 = (ws[30] != 0.0f);  // written by ece_zero_ws this call
    __syncthreads();

    const int lane = threadIdx.x & 63;
    const int half = lane >> 5;    // which row of the pair this lane serves
    const int hl   = lane & 31;    // lane within the 32-lane half
    const int wave_in_block   = threadIdx.x >> 6;
    const int waves_per_block = blockDim.x >> 6;
    const long long wave_global =
        (long long)blockIdx.x * waves_per_block + wave_in_block;
    const long long nwaves = (long long)gridDim.x * waves_per_block;
    const long long npairs = ((long long)n + 1) >> 1;

    // upper bin edges (searchsorted-left: bin = #edges strictly < conf, clip 9)
    const float ue[9] = {0.1f, 0.2f, 0.3f, 0.4f, 0.5f, 0.6f, 0.7f, 0.8f, 0.9f};

    for (long long pair = wave_global; pair < npairs; pair += nwaves) {
        const long long row = pair * 2 + half;
        if (row >= n) continue;  // uniform within each 32-lane half -> shfl-safe

        const float4 v =
            *reinterpret_cast<const float4*>(logits + pair * 256 + lane * 4);

        // lane-local max of 4 + index (strict > keeps lowest index on ties)
        float m = v.x;
        int idx = hl * 4;
        if (v.y > m) { m = v.y; idx = hl * 4 + 1; }
        if (v.z > m) { m = v.z; idx = hl * 4 + 2; }
        if (v.w > m) { m = v.w; idx = hl * 4 + 3; }

        // half-wave max+argmax reduce (xor offsets < 32 stay within the half)
        #pragma unroll
        for (int off = 16; off >= 1; off >>= 1) {
            float om = __shfl_xor(m, off, 64);
            int   oi = __shfl_xor(idx, off, 64);
            if (om > m || (om == m && oi < idx)) { m = om; idx = oi; }
        }

        // sum of exp(l - max); the max element contributes exp(0)=1 exactly,
        // so conf = 1/s matches max(softmax) structurally
        float s = __expf(v.x - m) + __expf(v.y - m) +
                  __expf(v.z - m) + __expf(v.w - m);
        #pragma unroll
        for (int off = 16; off >= 1; off >>= 1)
            s += __shfl_xor(s, off, 64);

        if (hl == 0) {
            float conf = 1.0f / s;
            int bin = 0;
            #pragma unroll
            for (int k = 0; k < 9; ++k) bin += (conf > ue[k]) ? 1 : 0;
            const int tgt = t64 ? targets[2 * row] : targets[row];
            float acc = (idx == tgt) ? 1.0f : 0.0f;
            atomicAdd(&s_cnt[bin], 1.0f);
            atomicAdd(&s_conf[bin], conf);
            atomicAdd(&s_acc[bin], acc);
        }
    }
    __syncthreads();

    if (threadIdx.x < NBINS) {
        atomicAdd(&ws[threadIdx.x],             s_cnt[threadIdx.x]);
        atomicAdd(&ws[NBINS + threadIdx.x],     s_conf[threadIdx.x]);
        atomicAdd(&ws[2 * NBINS + threadIdx.x], s_acc[threadIdx.x]);
    }
}

// --- kernel 2: scalar epilogue ---
__global__ void ece_final(const float* __restrict__ ws, float* __restrict__ out,
                          int n) {
    float ece = 0.0f;
    for (int b = 0; b < NBINS; ++b) {
        float cnt = ws[b];
        if (cnt > 0.0f) {
            float avg_conf = ws[NBINS + b] / cnt;
            float avg_acc  = ws[2 * NBINS + b] / cnt;
            float frac = cnt / (float)n;
            ece += fabsf(avg_conf - avg_acc) * frac;
        }
    }
    out[0] = ece;
}

extern "C" void kernel_launch(void* const* d_in, const int* in_sizes, int n_in,
                              void* d_out, int out_size, void* d_ws, size_t ws_size,
                              hipStream_t stream) {
    const float* logits = (const float*)d_in[0];
    const int* targets = (const int*)d_in[1];
    float* ws = (float*)d_ws;
    float* out = (float*)d_out;
    const int n = in_sizes[0] >> 7;  // rows = logits elements / 128 (dtype-proof)

    hipLaunchKernelGGL(ece_zero_ws, dim3(1), dim3(64), 0, stream, ws, targets);

    const int blocks = 2048;   // 8 blocks/CU, 32 waves/CU; grid-stride over pairs
    hipLaunchKernelGGL(ece_main, dim3(blocks), dim3(256), 0, stream,
                       logits, targets, ws, n);

    hipLaunchKernelGGL(ece_final, dim3(1), dim3(1), 0, stream, ws, out, n);
}